// Round 5
// baseline (167.062 us; speedup 1.0000x reference)
//
#include <hip/hip_runtime.h>

// Frames [B, T, C, H, W] = [8, 8, 3, 256, 256] fp32
#define BB 8
#define TT 8
#define HH 256
#define WW 256
#define FRAME_PIX (HH * WW)
#define R_BAND 4                         // output rows per wave
#define NBANDS (HH / R_BAND)             // 64
#define NPAIR (BB * (TT - 1))            // 56
#define NITEM (NPAIR * NBANDS)           // 3584 wave work-items
#define NBLK (NITEM / 4)                 // 896 blocks of 4 waves
#define EPS 1e-3f
#define INV_N (1.0f / (float)((size_t)NPAIR * 2 * HH * WW))

__device__ __forceinline__ float4 ld4(const float* __restrict__ p) {
    return *reinterpret_cast<const float4*>(p);
}
__device__ __forceinline__ float4 gray4(const float4 r, const float4 g, const float4 b) {
    float4 o;
    o.x = 0.2989f * r.x + 0.587f * g.x + 0.114f * b.x;
    o.y = 0.2989f * r.y + 0.587f * g.y + 0.114f * b.y;
    o.z = 0.2989f * r.z + 0.587f * g.z + 0.114f * b.z;
    o.w = 0.2989f * r.w + 0.587f * g.w + 0.114f * b.w;
    return o;
}

// One gray row fragment per lane: 4 px + left/right neighbors via shuffle.
struct GrayRow { float4 g; float L, R; };

__device__ __forceinline__ GrayRow make_row(const float4 r, const float4 g,
                                            const float4 b, const int lane) {
    GrayRow o;
    o.g = gray4(r, g, b);
    const float up = __shfl_up(o.g.w, 1, 64);
    const float dn = __shfl_down(o.g.x, 1, 64);
    o.L = (lane == 0)  ? 0.f : up;   // image col -1 (zero pad)
    o.R = (lane == 63) ? 0.f : dn;   // image col 256 (zero pad)
    return o;
}

// Sobel (cross-correlation, matches conv 'SAME' w/ zero pad) -> u,v for 4 px.
__device__ __forceinline__ void sobel_uv(const GrayRow& wt, const GrayRow& wm,
                                         const GrayRow& wb, const float4 g2v,
                                         float* __restrict__ u, float* __restrict__ v) {
    const float t_[6] = {wt.L, wt.g.x, wt.g.y, wt.g.z, wt.g.w, wt.R};
    const float m_[6] = {wm.L, wm.g.x, wm.g.y, wm.g.z, wm.g.w, wm.R};
    const float b_[6] = {wb.L, wb.g.x, wb.g.y, wb.g.z, wb.g.w, wb.R};
    const float g2a[4] = {g2v.x, g2v.y, g2v.z, g2v.w};
    #pragma unroll
    for (int c = 0; c < 4; ++c) {
        const float Ix = (t_[c] - t_[c + 2]) + 2.f * (m_[c] - m_[c + 2]) + (b_[c] - b_[c + 2]);
        const float Iy = (t_[c] + 2.f * t_[c + 1] + t_[c + 2])
                       - (b_[c] + 2.f * b_[c + 1] + b_[c + 2]);
        const float It = g2a[c] - m_[c + 1];
        const float inv = 1.f / (Ix * Ix + Iy * Iy + EPS);
        u[c] = -(Ix * It) * inv;
        v[c] = -(Iy * It) * inv;
    }
}

// Wave-autonomous: each wave processes one (pair, 4-row band). No LDS, no
// __syncthreads in the hot path — rolling 3-row gray window in registers,
// column halo via lane shuffles, rows stream downward with 12 independent
// float4 loads per step. Pair-major block order keeps the second read of
// each interior frame (as I1 of pair t+1) temporally close -> L3 hit.
__global__ __launch_bounds__(256, 3) void flow_loss_kernel(
    const float* __restrict__ pred, const float* __restrict__ gt,
    float* __restrict__ partial)
{
    const int tid   = threadIdx.x;
    const int lane  = tid & 63;
    const int witem = blockIdx.x * 4 + (tid >> 6);
    const int pair  = witem >> 6;            // NBANDS = 64
    const int band  = witem & (NBANDS - 1);
    const int b     = pair / (TT - 1);
    const int t     = pair % (TT - 1);

    const size_t fs = (size_t)3 * FRAME_PIX;
    const float* pt = pred + ((size_t)b * TT + t) * fs;   // pred frame t
    const float* p2 = pt + fs;                            // pred frame t+1
    const float* g1 = gt + ((size_t)b * TT + t) * fs;     // gt frame t
    const float* g2 = g1 + fs;                            // gt frame t+1

    const int y0 = band * R_BAND;
    int off = (y0 - 1) * WW + lane * 4;      // row y0-1 (may be invalid)

    GrayRow wp0, wp1, wp2, wg0, wg1, wg2;    // window rows y-1, y, y+1
    float4 c1r, c1g, c1b;                    // gt frame-t channels at row y (for mm)

    // ---- Prologue: rows y0-1 and y0 of frame t (both images) ----
    {
        float4 ar = {0,0,0,0}, ag = ar, ab_ = ar, br = ar, bg = ar, bb_ = ar;
        if (y0 > 0) {
            ar = ld4(pt + off); ag = ld4(pt + off + FRAME_PIX); ab_ = ld4(pt + off + 2 * FRAME_PIX);
            br = ld4(g1 + off); bg = ld4(g1 + off + FRAME_PIX); bb_ = ld4(g1 + off + 2 * FRAME_PIX);
        }
        wp0 = make_row(ar, ag, ab_, lane);
        wg0 = make_row(br, bg, bb_, lane);
    }
    off += WW;                               // row y0 (always valid)
    {
        const float4 ar = ld4(pt + off), ag = ld4(pt + off + FRAME_PIX),
                     ab_ = ld4(pt + off + 2 * FRAME_PIX);
        c1r = ld4(g1 + off); c1g = ld4(g1 + off + FRAME_PIX); c1b = ld4(g1 + off + 2 * FRAME_PIX);
        wp1 = make_row(ar, ag, ab_, lane);
        wg1 = make_row(c1r, c1g, c1b, lane);
    }
    off += WW;                               // row y0+1

    float s = 0.f;
    #pragma unroll
    for (int j = 0; j < R_BAND; ++j) {
        const int y = y0 + j;
        const bool vld = (y + 1) < HH;       // wave-uniform

        // Frame-t row y+1 (window advance) — 6 loads
        float4 ar = {0,0,0,0}, ag = ar, ab_ = ar, br = ar, bg = ar, bb_ = ar;
        if (vld) {
            ar = ld4(pt + off); ag = ld4(pt + off + FRAME_PIX); ab_ = ld4(pt + off + 2 * FRAME_PIX);
            br = ld4(g1 + off); bg = ld4(g1 + off + FRAME_PIX); bb_ = ld4(g1 + off + 2 * FRAME_PIX);
        }
        // Frame-t+1 row y (It + motion mag) — 6 loads, always valid
        const int off2 = off - WW;
        const float4 pr2 = ld4(p2 + off2), pg2 = ld4(p2 + off2 + FRAME_PIX),
                     pb2 = ld4(p2 + off2 + 2 * FRAME_PIX);
        const float4 gr2 = ld4(g2 + off2), gg2c = ld4(g2 + off2 + FRAME_PIX),
                     gb2 = ld4(g2 + off2 + 2 * FRAME_PIX);

        wp2 = make_row(ar, ag, ab_, lane);
        wg2 = make_row(br, bg, bb_, lane);
        const float4 gp2v = gray4(pr2, pg2, pb2);
        const float4 gg2v = gray4(gr2, gg2c, gb2);

        float mm[4];
        mm[0] = (fabsf(gr2.x - c1r.x) + fabsf(gg2c.x - c1g.x) + fabsf(gb2.x - c1b.x)) * (1.f / 3.f);
        mm[1] = (fabsf(gr2.y - c1r.y) + fabsf(gg2c.y - c1g.y) + fabsf(gb2.y - c1b.y)) * (1.f / 3.f);
        mm[2] = (fabsf(gr2.z - c1r.z) + fabsf(gg2c.z - c1g.z) + fabsf(gb2.z - c1b.z)) * (1.f / 3.f);
        mm[3] = (fabsf(gr2.w - c1r.w) + fabsf(gg2c.w - c1g.w) + fabsf(gb2.w - c1b.w)) * (1.f / 3.f);

        float up[4], vp[4], ug[4], vg[4];
        sobel_uv(wp0, wp1, wp2, gp2v, up, vp);
        sobel_uv(wg0, wg1, wg2, gg2v, ug, vg);
        #pragma unroll
        for (int c = 0; c < 4; ++c)
            s += (fabsf(up[c] - ug[c]) + fabsf(vp[c] - vg[c])) * mm[c];

        // Rotate window; carry gt frame-t channels of row y+1 for next mm
        wp0 = wp1; wp1 = wp2; wg0 = wg1; wg1 = wg2;
        c1r = br; c1g = bg; c1b = bb_;
        off += WW;
    }

    // ---- Wave reduce, then tiny block combine (single barrier at end) ----
    #pragma unroll
    for (int o = 32; o > 0; o >>= 1) s += __shfl_down(s, o, 64);

    __shared__ float wsum[4];
    if (lane == 0) wsum[tid >> 6] = s;
    __syncthreads();
    if (tid == 0)
        partial[blockIdx.x] = (wsum[0] + wsum[1]) + (wsum[2] + wsum[3]);
}

__global__ __launch_bounds__(256) void reduce_kernel(
    const float* __restrict__ partial, float* __restrict__ out)
{
    const int i = threadIdx.x;
    float s = partial[i] + partial[i + 256] + partial[i + 512];
    if (i < NBLK - 768) s += partial[i + 768];     // NBLK = 896
    #pragma unroll
    for (int o = 32; o > 0; o >>= 1) s += __shfl_down(s, o, 64);

    __shared__ float wsum[4];
    if ((i & 63) == 0) wsum[i >> 6] = s;
    __syncthreads();
    if (i == 0)
        out[0] = ((wsum[0] + wsum[1]) + (wsum[2] + wsum[3])) * INV_N;
}

extern "C" void kernel_launch(void* const* d_in, const int* in_sizes, int n_in,
                              void* d_out, int out_size, void* d_ws, size_t ws_size,
                              hipStream_t stream) {
    const float* pred = (const float*)d_in[0];
    const float* gt   = (const float*)d_in[1];
    float* partial    = (float*)d_ws;     // NBLK floats = 3584 B
    float* out        = (float*)d_out;

    flow_loss_kernel<<<dim3(NBLK), dim3(256), 0, stream>>>(pred, gt, partial);
    reduce_kernel<<<dim3(1), dim3(256), 0, stream>>>(partial, out);
}

// Round 7
// 131.235 us; speedup vs baseline: 1.2730x; 1.2730x over previous
//
#include <hip/hip_runtime.h>

// Frames [B, T, C, H, W] = [8, 8, 3, 256, 256] fp32
#define BB 8
#define TT 8
#define HH 256
#define WW 256
#define FRAME_PIX (HH * WW)
#define XW 128                       // tile width
#define RROWS 8                      // tile rows
#define NYT (HH / RROWS)             // 32
#define NXT (WW / XW)                // 2
#define PADW 136                     // 4 pad + 128 + 4 pad floats
#define NBLK (BB * 2 * NYT * NXT)    // 1024 blocks
#define EPS 1e-3f
#define INV_N (1.0f / (float)((size_t)BB * (TT - 1) * 2 * HH * WW))

// Native clang vector type: __builtin_nontemporal_load requires it
// (HIP_vector_type float4 is a struct and is rejected).
typedef float floatx4 __attribute__((ext_vector_type(4)));

// Non-temporal float4 load: all global data here is single-use streaming.
__device__ __forceinline__ float4 ld4nt(const float* __restrict__ p) {
    const floatx4 v = __builtin_nontemporal_load(
        reinterpret_cast<const floatx4*>(p));
    return make_float4(v.x, v.y, v.z, v.w);
}
__device__ __forceinline__ void st4(float* p, const float4 v) {
    *reinterpret_cast<float4*>(p) = v;
}
__device__ __forceinline__ float4 gray4(const float4 r, const float4 g, const float4 b) {
    float4 o;
    o.x = 0.2989f * r.x + 0.587f * g.x + 0.114f * b.x;
    o.y = 0.2989f * r.y + 0.587f * g.y + 0.114f * b.y;
    o.z = 0.2989f * r.z + 0.587f * g.z + 0.114f * b.z;
    o.w = 0.2989f * r.w + 0.587f * g.w + 0.114f * b.w;
    return o;
}

// Block = 128x8 tile of one batch element marching over a frame run
// (half 0: pairs 0..3 / frames 0..4; half 1: pairs 4..6 / frames 4..7).
// Frame channels are loaded from global exactly once per block: gray of
// frame t+1 is computed in regs during pair t's compute and rotated into
// LDS. gt channels of frame t carry in regs for motion magnitude.
// All global reads are non-temporal (single-use stream).
__global__ __launch_bounds__(256, 4) void flow_loss_kernel(
    const float* __restrict__ pred, const float* __restrict__ gt,
    float* __restrict__ partial)
{
    __shared__ float gbuf[2][RROWS + 2][PADW];   // 10880 B; row 0 = y0-1

    const int ytile = blockIdx.x >> 1;
    const int xtile = blockIdx.x & 1;
    const int half  = blockIdx.y;
    const int b     = blockIdx.z;
    const int t0    = half * 4;
    const int tend  = t0 + (half ? 3 : 4);
    const int y0    = ytile * RROWS;
    const int x0    = xtile * XW;
    const int tid   = threadIdx.x;
    const size_t fs = (size_t)3 * FRAME_PIX;
    const float* pb = pred + (size_t)b * TT * fs;
    const float* gb = gt   + (size_t)b * TT * fs;

    // compute mapping: row r (0..7), 4 px at col cx (0..124)
    const int r  = tid >> 5;
    const int cx = (tid & 31) * 4;
    const size_t coff = (size_t)(y0 + r) * WW + (x0 + cx);

    // "extra" staging role: tid<128 -> halo rows; 128..167 -> side pads
    bool e_act = false, e_val = false;
    int  e_img = 0;
    size_t e_off = 0;
    float* e_dst = &gbuf[0][0][0];
    if (tid < 128) {
        e_act = true;
        e_img = tid >> 6;
        const int rsel = (tid >> 5) & 1;
        const int ec   = (tid & 31) * 4;
        const int ey   = rsel ? (y0 + RROWS) : (y0 - 1);
        e_val = (unsigned)ey < HH;
        e_off = e_val ? ((size_t)ey * WW + x0 + ec) : 0;
        e_dst = &gbuf[e_img][rsel ? RROWS + 1 : 0][4 + ec];
    } else if (tid < 168) {
        const int j = tid - 128;
        e_act = true;
        e_img = j / 20;
        const int rem  = j % 20;
        const int side = rem / 10;
        const int prow = rem % 10;
        const int ey = y0 - 1 + prow;
        const int ex = side ? (x0 + XW) : (x0 - 4);
        e_val = ((unsigned)ey < HH) && ((unsigned)ex < WW);
        e_off = e_val ? ((size_t)ey * WW + ex) : 0;
        e_dst = &gbuf[e_img][prow][side ? 4 + XW : 0];
    }

    float4 g1c[3];   // gt frame-t channels at this thread's 4 px (for mm)

    // ---- Prologue: stage gray of frame t0 (center + halo), keep g1c ----
    {
        const float* p1 = pb + (size_t)t0 * fs;
        const float* g1 = gb + (size_t)t0 * fs;
        const float4 pr  = ld4nt(p1 + coff);
        const float4 pg  = ld4nt(p1 + coff + FRAME_PIX);
        const float4 pbl = ld4nt(p1 + coff + 2 * FRAME_PIX);
        g1c[0] = ld4nt(g1 + coff);
        g1c[1] = ld4nt(g1 + coff + FRAME_PIX);
        g1c[2] = ld4nt(g1 + coff + 2 * FRAME_PIX);
        const float* eb = e_img ? g1 : p1;
        float4 x0v = make_float4(0.f,0.f,0.f,0.f), x1v = x0v, x2v = x0v;
        if (e_act && e_val) {
            x0v = ld4nt(eb + e_off);
            x1v = ld4nt(eb + e_off + FRAME_PIX);
            x2v = ld4nt(eb + e_off + 2 * FRAME_PIX);
        }
        st4(&gbuf[0][r + 1][4 + cx], gray4(pr, pg, pbl));
        st4(&gbuf[1][r + 1][4 + cx], gray4(g1c[0], g1c[1], g1c[2]));
        if (e_act) st4(e_dst, gray4(x0v, x1v, x2v));
    }
    __syncthreads();

    float s = 0.f;
    for (int t = t0; t < tend; ++t) {
        const float* p2 = pb + (size_t)(t + 1) * fs;
        const float* g2 = gb + (size_t)(t + 1) * fs;

        // Load frame t+1 (center channels + halo extras), all independent NT
        float4 p2c[3], g2c[3], ecur[3];
        p2c[0] = ld4nt(p2 + coff);
        p2c[1] = ld4nt(p2 + coff + FRAME_PIX);
        p2c[2] = ld4nt(p2 + coff + 2 * FRAME_PIX);
        g2c[0] = ld4nt(g2 + coff);
        g2c[1] = ld4nt(g2 + coff + FRAME_PIX);
        g2c[2] = ld4nt(g2 + coff + 2 * FRAME_PIX);
        const float* eb = e_img ? g2 : p2;
        ecur[0] = make_float4(0.f,0.f,0.f,0.f); ecur[1] = ecur[0]; ecur[2] = ecur[0];
        if (e_act && e_val) {
            ecur[0] = ld4nt(eb + e_off);
            ecur[1] = ld4nt(eb + e_off + FRAME_PIX);
            ecur[2] = ld4nt(eb + e_off + 2 * FRAME_PIX);
        }

        const float4 gp2 = gray4(p2c[0], p2c[1], p2c[2]);
        const float4 gg2 = gray4(g2c[0], g2c[1], g2c[2]);

        float mm[4];
        mm[0] = (fabsf(g2c[0].x - g1c[0].x) + fabsf(g2c[1].x - g1c[1].x) + fabsf(g2c[2].x - g1c[2].x)) * (1.f/3.f);
        mm[1] = (fabsf(g2c[0].y - g1c[0].y) + fabsf(g2c[1].y - g1c[1].y) + fabsf(g2c[2].y - g1c[2].y)) * (1.f/3.f);
        mm[2] = (fabsf(g2c[0].z - g1c[0].z) + fabsf(g2c[1].z - g1c[1].z) + fabsf(g2c[2].z - g1c[2].z)) * (1.f/3.f);
        mm[3] = (fabsf(g2c[0].w - g1c[0].w) + fabsf(g2c[1].w - g1c[1].w) + fabsf(g2c[2].w - g1c[2].w)) * (1.f/3.f);

        // Pair-t compute: Sobel on gray(t) in LDS, It vs gray(t+1) in regs
        float up[4], vp[4];
        #pragma unroll
        for (int img = 0; img < 2; ++img) {
            // padded floats cx+3..cx+8 -> aligned float4s at cx, cx+4, cx+8
            float w0[6], w1[6], w2[6];
            {
                const float* p = &gbuf[img][r][cx];
                const float4 A = *(const float4*)p, B = *(const float4*)(p + 4), C = *(const float4*)(p + 8);
                w0[0] = A.w; w0[1] = B.x; w0[2] = B.y; w0[3] = B.z; w0[4] = B.w; w0[5] = C.x;
            }
            {
                const float* p = &gbuf[img][r + 1][cx];
                const float4 A = *(const float4*)p, B = *(const float4*)(p + 4), C = *(const float4*)(p + 8);
                w1[0] = A.w; w1[1] = B.x; w1[2] = B.y; w1[3] = B.z; w1[4] = B.w; w1[5] = C.x;
            }
            {
                const float* p = &gbuf[img][r + 2][cx];
                const float4 A = *(const float4*)p, B = *(const float4*)(p + 4), C = *(const float4*)(p + 8);
                w2[0] = A.w; w2[1] = B.x; w2[2] = B.y; w2[3] = B.z; w2[4] = B.w; w2[5] = C.x;
            }
            const float4 gr2 = img ? gg2 : gp2;
            const float g2a[4] = {gr2.x, gr2.y, gr2.z, gr2.w};
            #pragma unroll
            for (int j = 0; j < 4; ++j) {
                const float Ix = (w0[j] - w0[j + 2]) + 2.0f * (w1[j] - w1[j + 2]) + (w2[j] - w2[j + 2]);
                const float Iy = (w0[j] + 2.0f * w0[j + 1] + w0[j + 2])
                               - (w2[j] + 2.0f * w2[j + 1] + w2[j + 2]);
                const float It = g2a[j] - w1[j + 1];
                const float inv = 1.0f / (Ix * Ix + Iy * Iy + EPS);
                if (img == 0) {
                    up[j] = -(Ix * It) * inv;
                    vp[j] = -(Iy * It) * inv;
                } else {
                    s += (fabsf(up[j] + (Ix * It) * inv) + fabsf(vp[j] + (Iy * It) * inv)) * mm[j];
                }
            }
        }

        if (t + 1 < tend) {
            __syncthreads();
            // Rotate: gray(t+1) into LDS; carry gt channels for next mm
            st4(&gbuf[0][r + 1][4 + cx], gp2);
            st4(&gbuf[1][r + 1][4 + cx], gg2);
            if (e_act) st4(e_dst, gray4(ecur[0], ecur[1], ecur[2]));
            g1c[0] = g2c[0]; g1c[1] = g2c[1]; g1c[2] = g2c[2];
            __syncthreads();
        }
    }

    // ---- Block reduction -> one partial per block ----
    #pragma unroll
    for (int off = 32; off > 0; off >>= 1) s += __shfl_down(s, off, 64);

    __shared__ float wsum[4];
    if ((tid & 63) == 0) wsum[tid >> 6] = s;
    __syncthreads();
    if (tid == 0) {
        partial[(b * 2 + half) * (NYT * NXT) + blockIdx.x] =
            wsum[0] + wsum[1] + wsum[2] + wsum[3];
    }
}

__global__ __launch_bounds__(256) void reduce_kernel(
    const float* __restrict__ partial, float* __restrict__ out)
{
    const float4 v = *reinterpret_cast<const float4*>(partial + threadIdx.x * 4);
    float s = (v.x + v.y) + (v.z + v.w);
    #pragma unroll
    for (int off = 32; off > 0; off >>= 1) s += __shfl_down(s, off, 64);

    __shared__ float wsum[4];
    if ((threadIdx.x & 63) == 0) wsum[threadIdx.x >> 6] = s;
    __syncthreads();
    if (threadIdx.x == 0) {
        out[0] = (wsum[0] + wsum[1] + wsum[2] + wsum[3]) * INV_N;
    }
}

extern "C" void kernel_launch(void* const* d_in, const int* in_sizes, int n_in,
                              void* d_out, int out_size, void* d_ws, size_t ws_size,
                              hipStream_t stream) {
    const float* pred = (const float*)d_in[0];
    const float* gt   = (const float*)d_in[1];
    float* partial    = (float*)d_ws;     // NBLK floats = 4096 B
    float* out        = (float*)d_out;

    dim3 grid(NYT * NXT, 2, BB);          // (64, 2, 8) = 1024 blocks
    dim3 block(256);
    flow_loss_kernel<<<grid, block, 0, stream>>>(pred, gt, partial);
    reduce_kernel<<<1, 256, 0, stream>>>(partial, out);
}

// Round 8
// 126.044 us; speedup vs baseline: 1.3254x; 1.0412x over previous
//
#include <hip/hip_runtime.h>

// Frames [B, T, C, H, W] = [8, 8, 3, 256, 256] fp32
#define BB 8
#define TT 8
#define HH 256
#define WW 256
#define FRAME_PIX (HH * WW)
#define XW 128                       // tile width
#define RROWS 8                      // tile rows
#define NYT (HH / RROWS)             // 32
#define NXT (WW / XW)                // 2
#define PADW 136                     // 4 pad + 128 + 4 pad floats
#define EPS 1e-3f
#define INV_N (1.0f / (float)((size_t)BB * (TT - 1) * 2 * HH * WW))

__device__ __forceinline__ float4 ld4(const float* __restrict__ p) {
    return *reinterpret_cast<const float4*>(p);
}
__device__ __forceinline__ void st4(float* p, const float4 v) {
    *reinterpret_cast<float4*>(p) = v;
}
__device__ __forceinline__ float4 gray4(const float4 r, const float4 g, const float4 b) {
    float4 o;
    o.x = 0.2989f * r.x + 0.587f * g.x + 0.114f * b.x;
    o.y = 0.2989f * r.y + 0.587f * g.y + 0.114f * b.y;
    o.z = 0.2989f * r.z + 0.587f * g.z + 0.114f * b.z;
    o.w = 0.2989f * r.w + 0.587f * g.w + 0.114f * b.w;
    return o;
}

// Block = 128x8 tile of one batch element marching over a frame run
// (half 0: pairs 0..3 / frames 0..4; half 1: pairs 4..6 / frames 4..7).
// Frame channels loaded from global once per block; gray of frame t+1
// computed in regs during pair t's compute and rotated into LDS. gt
// channels of frame t carry in regs for motion magnitude. Final loss is
// accumulated with one device-scope float atomicAdd per block (d_out is
// zeroed by a capture-safe hipMemsetAsync before the kernel).
// NOTE: nontemporal loads tried in R7 regressed 10 us (L3 stops absorbing
// re-reads); plain loads are correct here. Read BW is MSHR-wall-bound at
// ~2.9 TB/s regardless of structure.
__global__ __launch_bounds__(256, 4) void flow_loss_kernel(
    const float* __restrict__ pred, const float* __restrict__ gt,
    float* __restrict__ out)
{
    __shared__ float gbuf[2][RROWS + 2][PADW];   // 10880 B; row 0 = y0-1

    const int ytile = blockIdx.x >> 1;
    const int xtile = blockIdx.x & 1;
    const int half  = blockIdx.y;
    const int b     = blockIdx.z;
    const int t0    = half * 4;
    const int tend  = t0 + (half ? 3 : 4);
    const int y0    = ytile * RROWS;
    const int x0    = xtile * XW;
    const int tid   = threadIdx.x;
    const size_t fs = (size_t)3 * FRAME_PIX;
    const float* pb = pred + (size_t)b * TT * fs;
    const float* gb = gt   + (size_t)b * TT * fs;

    // compute mapping: row r (0..7), 4 px at col cx (0..124)
    const int r  = tid >> 5;
    const int cx = (tid & 31) * 4;
    const size_t coff = (size_t)(y0 + r) * WW + (x0 + cx);

    // "extra" staging role: tid<128 -> halo rows; 128..167 -> side pads
    bool e_act = false, e_val = false;
    int  e_img = 0;
    size_t e_off = 0;
    float* e_dst = &gbuf[0][0][0];
    if (tid < 128) {
        e_act = true;
        e_img = tid >> 6;
        const int rsel = (tid >> 5) & 1;
        const int ec   = (tid & 31) * 4;
        const int ey   = rsel ? (y0 + RROWS) : (y0 - 1);
        e_val = (unsigned)ey < HH;
        e_off = e_val ? ((size_t)ey * WW + x0 + ec) : 0;
        e_dst = &gbuf[e_img][rsel ? RROWS + 1 : 0][4 + ec];
    } else if (tid < 168) {
        const int j = tid - 128;
        e_act = true;
        e_img = j / 20;
        const int rem  = j % 20;
        const int side = rem / 10;
        const int prow = rem % 10;
        const int ey = y0 - 1 + prow;
        const int ex = side ? (x0 + XW) : (x0 - 4);
        e_val = ((unsigned)ey < HH) && ((unsigned)ex < WW);
        e_off = e_val ? ((size_t)ey * WW + ex) : 0;
        e_dst = &gbuf[e_img][prow][side ? 4 + XW : 0];
    }

    float4 g1c[3];   // gt frame-t channels at this thread's 4 px (for mm)

    // ---- Prologue: stage gray of frame t0 (center + halo), keep g1c ----
    {
        const float* p1 = pb + (size_t)t0 * fs;
        const float* g1 = gb + (size_t)t0 * fs;
        const float4 pr  = ld4(p1 + coff);
        const float4 pg  = ld4(p1 + coff + FRAME_PIX);
        const float4 pbl = ld4(p1 + coff + 2 * FRAME_PIX);
        g1c[0] = ld4(g1 + coff);
        g1c[1] = ld4(g1 + coff + FRAME_PIX);
        g1c[2] = ld4(g1 + coff + 2 * FRAME_PIX);
        const float* eb = e_img ? g1 : p1;
        float4 x0v = make_float4(0.f,0.f,0.f,0.f), x1v = x0v, x2v = x0v;
        if (e_act && e_val) {
            x0v = ld4(eb + e_off);
            x1v = ld4(eb + e_off + FRAME_PIX);
            x2v = ld4(eb + e_off + 2 * FRAME_PIX);
        }
        st4(&gbuf[0][r + 1][4 + cx], gray4(pr, pg, pbl));
        st4(&gbuf[1][r + 1][4 + cx], gray4(g1c[0], g1c[1], g1c[2]));
        if (e_act) st4(e_dst, gray4(x0v, x1v, x2v));
    }
    __syncthreads();

    float s = 0.f;
    for (int t = t0; t < tend; ++t) {
        const float* p2 = pb + (size_t)(t + 1) * fs;
        const float* g2 = gb + (size_t)(t + 1) * fs;

        // Load frame t+1 (center channels + halo extras), all independent
        float4 p2c[3], g2c[3], ecur[3];
        p2c[0] = ld4(p2 + coff);
        p2c[1] = ld4(p2 + coff + FRAME_PIX);
        p2c[2] = ld4(p2 + coff + 2 * FRAME_PIX);
        g2c[0] = ld4(g2 + coff);
        g2c[1] = ld4(g2 + coff + FRAME_PIX);
        g2c[2] = ld4(g2 + coff + 2 * FRAME_PIX);
        const float* eb = e_img ? g2 : p2;
        ecur[0] = make_float4(0.f,0.f,0.f,0.f); ecur[1] = ecur[0]; ecur[2] = ecur[0];
        if (e_act && e_val) {
            ecur[0] = ld4(eb + e_off);
            ecur[1] = ld4(eb + e_off + FRAME_PIX);
            ecur[2] = ld4(eb + e_off + 2 * FRAME_PIX);
        }

        const float4 gp2 = gray4(p2c[0], p2c[1], p2c[2]);
        const float4 gg2 = gray4(g2c[0], g2c[1], g2c[2]);

        float mm[4];
        mm[0] = (fabsf(g2c[0].x - g1c[0].x) + fabsf(g2c[1].x - g1c[1].x) + fabsf(g2c[2].x - g1c[2].x)) * (1.f/3.f);
        mm[1] = (fabsf(g2c[0].y - g1c[0].y) + fabsf(g2c[1].y - g1c[1].y) + fabsf(g2c[2].y - g1c[2].y)) * (1.f/3.f);
        mm[2] = (fabsf(g2c[0].z - g1c[0].z) + fabsf(g2c[1].z - g1c[1].z) + fabsf(g2c[2].z - g1c[2].z)) * (1.f/3.f);
        mm[3] = (fabsf(g2c[0].w - g1c[0].w) + fabsf(g2c[1].w - g1c[1].w) + fabsf(g2c[2].w - g1c[2].w)) * (1.f/3.f);

        // Pair-t compute: Sobel on gray(t) in LDS, It vs gray(t+1) in regs
        float up[4], vp[4];
        #pragma unroll
        for (int img = 0; img < 2; ++img) {
            // padded floats cx+3..cx+8 -> aligned float4s at cx, cx+4, cx+8
            float w0[6], w1[6], w2[6];
            {
                const float* p = &gbuf[img][r][cx];
                const float4 A = ld4(p), B = ld4(p + 4), C = ld4(p + 8);
                w0[0] = A.w; w0[1] = B.x; w0[2] = B.y; w0[3] = B.z; w0[4] = B.w; w0[5] = C.x;
            }
            {
                const float* p = &gbuf[img][r + 1][cx];
                const float4 A = ld4(p), B = ld4(p + 4), C = ld4(p + 8);
                w1[0] = A.w; w1[1] = B.x; w1[2] = B.y; w1[3] = B.z; w1[4] = B.w; w1[5] = C.x;
            }
            {
                const float* p = &gbuf[img][r + 2][cx];
                const float4 A = ld4(p), B = ld4(p + 4), C = ld4(p + 8);
                w2[0] = A.w; w2[1] = B.x; w2[2] = B.y; w2[3] = B.z; w2[4] = B.w; w2[5] = C.x;
            }
            const float4 gr2 = img ? gg2 : gp2;
            const float g2a[4] = {gr2.x, gr2.y, gr2.z, gr2.w};
            #pragma unroll
            for (int j = 0; j < 4; ++j) {
                const float Ix = (w0[j] - w0[j + 2]) + 2.0f * (w1[j] - w1[j + 2]) + (w2[j] - w2[j + 2]);
                const float Iy = (w0[j] + 2.0f * w0[j + 1] + w0[j + 2])
                               - (w2[j] + 2.0f * w2[j + 1] + w2[j + 2]);
                const float It = g2a[j] - w1[j + 1];
                const float inv = 1.0f / (Ix * Ix + Iy * Iy + EPS);
                if (img == 0) {
                    up[j] = -(Ix * It) * inv;
                    vp[j] = -(Iy * It) * inv;
                } else {
                    s += (fabsf(up[j] + (Ix * It) * inv) + fabsf(vp[j] + (Iy * It) * inv)) * mm[j];
                }
            }
        }

        if (t + 1 < tend) {
            __syncthreads();
            // Rotate: gray(t+1) into LDS; carry gt channels for next mm
            st4(&gbuf[0][r + 1][4 + cx], gp2);
            st4(&gbuf[1][r + 1][4 + cx], gg2);
            if (e_act) st4(e_dst, gray4(ecur[0], ecur[1], ecur[2]));
            g1c[0] = g2c[0]; g1c[1] = g2c[1]; g1c[2] = g2c[2];
            __syncthreads();
        }
    }

    // ---- Block reduction -> one scaled atomicAdd per block ----
    #pragma unroll
    for (int off = 32; off > 0; off >>= 1) s += __shfl_down(s, off, 64);

    __shared__ float wsum[4];
    if ((tid & 63) == 0) wsum[tid >> 6] = s;
    __syncthreads();
    if (tid == 0) {
        const float bs = (wsum[0] + wsum[1]) + (wsum[2] + wsum[3]);
        atomicAdd(out, bs * INV_N);   // device-scope (cross-XCD safe)
    }
}

extern "C" void kernel_launch(void* const* d_in, const int* in_sizes, int n_in,
                              void* d_out, int out_size, void* d_ws, size_t ws_size,
                              hipStream_t stream) {
    const float* pred = (const float*)d_in[0];
    const float* gt   = (const float*)d_in[1];
    float* out        = (float*)d_out;

    // d_out is re-poisoned to 0xAA before every timed launch; zero it
    // (capture-safe: becomes a memset node in the graph).
    hipMemsetAsync(out, 0, sizeof(float), stream);

    dim3 grid(NYT * NXT, 2, BB);          // (64, 2, 8) = 1024 blocks
    dim3 block(256);
    flow_loss_kernel<<<grid, block, 0, stream>>>(pred, gt, out);
}